// Round 2
// baseline (2791.961 us; speedup 1.0000x reference)
//
#include <hip/hip_runtime.h>
#include <hip/hip_bf16.h>
#include <cstdint>
#include <cstddef>

typedef unsigned short u16;
typedef __attribute__((ext_vector_type(8))) __bf16 bf16x8;
typedef __attribute__((ext_vector_type(4))) float floatx4;

#define B_ 8
#define S_ 2048
#define D_ 1024
#define H_ 4096
#define E_ 8

__device__ __forceinline__ u16 f2bf(float f) {
    union { float f; unsigned u; } c; c.f = f;
    return (u16)((c.u + 0x7fffu + ((c.u >> 16) & 1u)) >> 16);  // RNE, finite inputs
}

__device__ __forceinline__ void gload16(const void* g, void* l) {
    __builtin_amdgcn_global_load_lds((__attribute__((address_space(1))) void*)(g),
                                     (__attribute__((address_space(3))) void*)(l),
                                     16, 0, 0);
}

// ---- LDS tile layout (PROVEN m97-family swizzle; rows of 64 K = 128 B = 8 chunks of 16 B)
// Slot j holds (row r=j>>3, chunk c=(j&7)^(r&7)).  fragld(row, c) reads chunk c of row.
__device__ __forceinline__ bf16x8 fragld(const u16* lds, int row, int c) {
    return *(const bf16x8*)(lds + (((row << 3) + (c ^ (row & 7))) << 3));
}

// ===================== tier-C staging helpers (fallback path) =====================
__device__ __forceinline__ void stage(const u16* gbase, int ld, u16* lds, int tid) {
    int wid = tid >> 6;
#pragma unroll
    for (int q = 0; q < 4; ++q) {
        int j = q * 256 + tid;
        int r = j >> 3;
        int c = (j & 7) ^ (r & 7);
        gload16(gbase + (size_t)r * ld + c * 8,
                lds + (size_t)(q * 256 + wid * 64) * 8);
    }
}

__device__ __forceinline__ void stageF(const float* gbase, int ld, u16* lds, int tid) {
#pragma unroll
    for (int q = 0; q < 4; ++q) {
        int j = q * 256 + tid;
        int r = j >> 3;
        int c = (j & 7) ^ (r & 7);
        const float* src = gbase + (size_t)r * ld + c * 8;
        u16 tmp[8];
#pragma unroll
        for (int i = 0; i < 8; ++i) tmp[i] = f2bf(src[i]);
        *(uint4*)(lds + (size_t)j * 8) = *(uint4*)tmp;
    }
}

__device__ __forceinline__ void stageKTF(const float* gbase, int ld, u16* lds, int tid) {
#pragma unroll
    for (int q = 0; q < 4; ++q) {
        int g = q * 256 + tid;
        int k = g >> 4;
        int nc = g & 15;
        const float* src = gbase + (size_t)k * ld + nc * 8;
        int kc = k >> 3, kl = k & 7;
#pragma unroll
        for (int i = 0; i < 8; ++i) {
            int n = nc * 8 + i;
            lds[(((n << 3) + (kc ^ (n & 7))) << 3) + kl] = f2bf(src[i]);
        }
    }
}

// ---------------- gate (fp32 throughout) ----------------
__global__ void mean1_kernel(const float* __restrict__ x, float* __restrict__ part) {
    int d = (blockIdx.x & 3) * 256 + threadIdx.x;
    int b = blockIdx.x >> 2;
    int sc = blockIdx.y;
    const float* p = x + (size_t)b * S_ * D_ + (size_t)sc * 256 * D_ + d;
    float s = 0.f;
#pragma unroll 8
    for (int i = 0; i < 256; ++i) s += p[(size_t)i * D_];
    part[((size_t)b * 8 + sc) * D_ + d] = s;
}

__global__ void mean2_kernel(const float* __restrict__ part, float* __restrict__ ri) {
    int d = (blockIdx.x & 3) * 256 + threadIdx.x;
    int b = blockIdx.x >> 2;
    float s = 0.f;
#pragma unroll
    for (int i = 0; i < 8; ++i) s += part[((size_t)b * 8 + i) * D_ + d];
    ri[b * D_ + d] = s * (1.0f / S_);
}

__global__ void gate1_kernel(const float* __restrict__ ri, const float* __restrict__ Wg1,
                             const float* __restrict__ bg1, float* __restrict__ gh) {
    int j = (blockIdx.x & 3) * 256 + threadIdx.x;
    int b = blockIdx.x >> 2;
    const float* r = ri + b * D_;
    float acc = 0.f;
    for (int i = 0; i < D_; ++i) acc += r[i] * Wg1[(size_t)i * D_ + j];
    acc += bg1[j];
    gh[b * D_ + j] = acc / (1.f + expf(-acc));
}

__global__ void gate2_kernel(const float* __restrict__ gh, const float* __restrict__ Wg2,
                             const float* __restrict__ bg2, float* __restrict__ wgate,
                             int* __restrict__ eidx, float* __restrict__ out) {
    __shared__ float lg[B_ * E_];
    int t = threadIdx.x;  // 64 threads: (b,e) pairs
    int b = t >> 3, e = t & 7;
    const float* g = gh + b * D_;
    float acc = 0.f;
    for (int i = 0; i < D_; ++i) acc += g[i] * Wg2[(size_t)i * E_ + e];
    acc += bg2[e];
    lg[t] = acc;
    __syncthreads();
    if (t < B_) {
        float l0 = -1e30f, l1 = -1e30f; int i0 = 0, i1 = 0;
        for (int ee = 0; ee < E_; ++ee) {
            float v = lg[t * E_ + ee];
            if (v > l0) { l1 = l0; i1 = i0; l0 = v; i0 = ee; }
            else if (v > l1) { l1 = v; i1 = ee; }
        }
        float e1 = expf(l1 - l0);
        float w0 = 1.f / (1.f + e1), w1 = e1 / (1.f + e1);
        wgate[t * 2] = w0; wgate[t * 2 + 1] = w1;
        eidx[t * 2] = i0;  eidx[t * 2 + 1] = i1;
        float* ow = out + (size_t)B_ * S_ * D_;        // tail: topk_w then topk_idx
        ow[t * 2] = w0;              ow[t * 2 + 1] = w1;
        ow[16 + t * 2] = (float)i0;  ow[16 + t * 2 + 1] = (float)i1;
    }
}

// ---------------- converters (tier A) ----------------
__global__ void convx_kernel(const float* __restrict__ in, u16* __restrict__ out) {
    size_t i = ((size_t)blockIdx.x * 256 + threadIdx.x) * 8;
    u16 tmp[8];
#pragma unroll
    for (int j = 0; j < 8; ++j) tmp[j] = f2bf(in[i + j]);
    *(uint4*)(out + i) = *(uint4*)tmp;
}

// in fp32 [E][R][C] -> out bf16 [E][C][R]
__global__ __launch_bounds__(256) void convT_kernel(const float* __restrict__ in,
                                                    u16* __restrict__ out,
                                                    int R, int C) {
    __shared__ __align__(16) u16 T[64][72];
    int e = blockIdx.z;
    const float* ine = in + (size_t)e * R * C;
    u16* oute = out + (size_t)e * R * C;
    int r0 = blockIdx.y * 64, c0 = blockIdx.x * 64;
    int tid = threadIdx.x;
#pragma unroll
    for (int q = 0; q < 2; ++q) {
        int j = q * 256 + tid;
        int r = j >> 3, ch = j & 7;
        const float* src = ine + (size_t)(r0 + r) * C + c0 + ch * 8;
        u16 tmp[8];
#pragma unroll
        for (int i = 0; i < 8; ++i) tmp[i] = f2bf(src[i]);
        *(uint4*)&T[r][ch * 8] = *(uint4*)tmp;
    }
    __syncthreads();
#pragma unroll
    for (int q = 0; q < 2; ++q) {
        int j = q * 256 + tid;
        int orow = j >> 3, och = j & 7;
        uint4 v; u16* pv = (u16*)&v;
#pragma unroll
        for (int i = 0; i < 8; ++i) pv[i] = T[och * 8 + i][orow];
        *(uint4*)(oute + (size_t)(c0 + orow) * R + r0 + och * 8) = v;
    }
}

// ===================== 256x256 free-running GEMMs (tier A) =====================
// BK=64, double-buffered (2x 32KB A + 2x 32KB B = 128 KiB LDS), 8 waves (2M x 4N),
// per-wave C = 128x64 (acc[8][4]).  Per 64-K tile: 24 ds_read_b128 + 64 MFMA,
// NO per-phase lockstep: compiler interleaves ds_read<->MFMA with fine lgkmcnt.
// Only 2 barriers per tile:
//   #1 after all frag reads are consumed  -> safe to issue gloads of tile t+2
//      into this buffer (they land >=L2-latency after issue, post-barrier).
//   #2 after per-wave vmcnt(8)            -> tile t+1's data (from ALL waves'
//      loads) has landed; next iteration may read it.
// vmcnt never drains to 0 in steady state (counted, T4): tile t+1's 8 loads are
// guaranteed landed while t+2's 8 stay in flight.

#define VM8  asm volatile("s_waitcnt vmcnt(8)" ::: "memory")
#define VM0  asm volatile("s_waitcnt vmcnt(0)" ::: "memory")
#define LG0  asm volatile("s_waitcnt lgkmcnt(0)" ::: "memory")

// per-thread setup shared by both v2 kernels; LDB = row stride in bytes
#define SETUP_V2(LDB) \
    const int tid = threadIdx.x, lane = tid & 63, wid = tid >> 6; \
    const int wr = wid >> 2, wc = wid & 3, lr = lane & 15, quad = lane >> 4; \
    int goff[4], dstg[4]; \
    _Pragma("unroll") for (int q = 0; q < 4; ++q) { \
        int j = q * 512 + tid, r = j >> 3, c = (j & 7) ^ (r & 7); \
        goff[q] = r * (LDB) + c * 16; \
        dstg[q] = (q * 512 + wid * 64) * 8; \
    } \
    floatx4 acc[8][4] = {};

// tile-t compute body: reads 24 frags, does 48 MFMA, barrier#1, STAGE, 16 MFMA, vmcnt, barrier#2
#define TILE_BODY(T, STAGE_STMT, VM_STMT) do { \
    const u16* sA = lA[(T) & 1]; \
    const u16* sB = lB[(T) & 1]; \
    bf16x8 bfv[4][2], a0[4][2], a1[4][2]; \
    _Pragma("unroll") for (int nt = 0; nt < 4; ++nt) \
        _Pragma("unroll") for (int ks = 0; ks < 2; ++ks) \
            bfv[nt][ks] = fragld(sB, wc * 64 + nt * 16 + lr, ks * 4 + quad); \
    _Pragma("unroll") for (int mt = 0; mt < 4; ++mt) \
        _Pragma("unroll") for (int ks = 0; ks < 2; ++ks) \
            a0[mt][ks] = fragld(sA, wr * 128 + mt * 16 + lr, ks * 4 + quad); \
    _Pragma("unroll") for (int mt = 0; mt < 4; ++mt) \
        _Pragma("unroll") for (int nt = 0; nt < 4; ++nt) \
            _Pragma("unroll") for (int ks = 0; ks < 2; ++ks) \
                acc[mt][nt] = __builtin_amdgcn_mfma_f32_16x16x32_bf16(a0[mt][ks], bfv[nt][ks], acc[mt][nt], 0, 0, 0); \
    _Pragma("unroll") for (int mt = 0; mt < 4; ++mt) \
        _Pragma("unroll") for (int ks = 0; ks < 2; ++ks) \
            a1[mt][ks] = fragld(sA, wr * 128 + 64 + mt * 16 + lr, ks * 4 + quad); \
    _Pragma("unroll") for (int mt = 0; mt < 4; ++mt) \
        _Pragma("unroll") for (int nt = 0; nt < 2; ++nt) \
            _Pragma("unroll") for (int ks = 0; ks < 2; ++ks) \
                acc[4 + mt][nt] = __builtin_amdgcn_mfma_f32_16x16x32_bf16(a1[mt][ks], bfv[nt][ks], acc[4 + mt][nt], 0, 0, 0); \
    LG0; \
    __builtin_amdgcn_s_barrier();  /* #1 */ \
    STAGE_STMT; \
    _Pragma("unroll") for (int mt = 0; mt < 4; ++mt) \
        _Pragma("unroll") for (int nt = 2; nt < 4; ++nt) \
            _Pragma("unroll") for (int ks = 0; ks < 2; ++ks) \
                acc[4 + mt][nt] = __builtin_amdgcn_mfma_f32_16x16x32_bf16(a1[mt][ks], bfv[nt][ks], acc[4 + mt][nt], 0, 0, 0); \
    VM_STMT; \
    __builtin_amdgcn_s_barrier();  /* #2 */ \
} while (0)

// GEMM1: hbuf[lp] = wk * silu(xb[b] @ W1T[e]^T + b1[e]); A,B row-major k-contig, ld=D_
__global__ __launch_bounds__(512, 2) void gemm1_v2(
    const u16* __restrict__ A, const u16* __restrict__ Bw,
    const float* __restrict__ b1, const int* __restrict__ eidx,
    const float* __restrict__ wgate, u16* __restrict__ hbuf,
    int s0, int hRows) {
    __shared__ __align__(16) u16 lA[2][16384];
    __shared__ __align__(16) u16 lB[2][16384];
    SETUP_V2(D_ * 2)
    const int lp = blockIdx.z, b = lp >> 1;
    const int e = eidx[lp];
    const float wk = wgate[lp];
    const char* Ab = (const char*)(A + (size_t)(b * S_ + s0 + blockIdx.y * 256) * D_);
    const char* Bb = (const char*)(Bw + (size_t)e * H_ * D_ + (size_t)(blockIdx.x * 256) * D_);
    const int NT = D_ / 64;  // 16

#define G1_STAGE(T) do { const int kb = (T) * 128, bi = (T) & 1; \
        _Pragma("unroll") for (int q = 0; q < 4; ++q) gload16(Ab + goff[q] + kb, &lA[bi][dstg[q]]); \
        _Pragma("unroll") for (int q = 0; q < 4; ++q) gload16(Bb + goff[q] + kb, &lB[bi][dstg[q]]); \
    } while (0)

    G1_STAGE(0); G1_STAGE(1);
    VM8;
    __builtin_amdgcn_s_barrier();

#pragma unroll 1
    for (int t = 0; t < NT; ++t) {
        if (t + 2 < NT)      TILE_BODY(t, G1_STAGE(t + 2), VM8);
        else if (t + 1 < NT) TILE_BODY(t, (void)0, VM0);
        else                 TILE_BODY(t, (void)0, (void)0);
    }
#undef G1_STAGE

#pragma unroll
    for (int am = 0; am < 8; ++am)
#pragma unroll
        for (int nt = 0; nt < 4; ++nt) {
            int n = blockIdx.x * 256 + wc * 64 + nt * 16 + lr;
            float bb = b1[e * H_ + n];
#pragma unroll
            for (int r = 0; r < 4; ++r) {
                int mrow = blockIdx.y * 256 + wr * 128 + (am >> 2) * 64 + (am & 3) * 16 + quad * 4 + r;
                float v = acc[am][nt][r] + bb;
                v = v / (1.f + __expf(-v)) * wk;
                hbuf[((size_t)lp * hRows + mrow) * H_ + n] = f2bf(v);
            }
        }
}

// GEMM2: out[b] = sum_kp hbuf[b*2+kp] @ W2T[e_kp]^T + sum w*b2; virtual K = 2*H_, ld=H_
__global__ __launch_bounds__(512, 2) void gemm2_v2(
    const u16* __restrict__ hbuf, const u16* __restrict__ Bw,
    const float* __restrict__ b2, const int* __restrict__ eidx,
    const float* __restrict__ wgate, float* __restrict__ out,
    int s0, int hRows) {
    __shared__ __align__(16) u16 lA[2][16384];
    __shared__ __align__(16) u16 lB[2][16384];
    SETUP_V2(H_ * 2)
    const int b = blockIdx.z;
    const int e0 = eidx[b * 2], e1 = eidx[b * 2 + 1];
    const float w0 = wgate[b * 2], w1 = wgate[b * 2 + 1];
    const char* Ab0 = (const char*)(hbuf + ((size_t)(b * 2) * hRows + blockIdx.y * 256) * H_);
    const char* Ab1 = (const char*)(hbuf + ((size_t)(b * 2 + 1) * hRows + blockIdx.y * 256) * H_);
    const char* Bb0 = (const char*)(Bw + (size_t)e0 * D_ * H_ + (size_t)(blockIdx.x * 256) * H_);
    const char* Bb1 = (const char*)(Bw + (size_t)e1 * D_ * H_ + (size_t)(blockIdx.x * 256) * H_);
    const int NT = 2 * H_ / 64;  // 128

#define G2_STAGE(T) do { const int tt = (T); const int kb = (tt & 63) * 128, bi = tt & 1; \
        const char* As_ = (tt & 64) ? Ab1 : Ab0; \
        const char* Bs_ = (tt & 64) ? Bb1 : Bb0; \
        _Pragma("unroll") for (int q = 0; q < 4; ++q) gload16(As_ + goff[q] + kb, &lA[bi][dstg[q]]); \
        _Pragma("unroll") for (int q = 0; q < 4; ++q) gload16(Bs_ + goff[q] + kb, &lB[bi][dstg[q]]); \
    } while (0)

    G2_STAGE(0); G2_STAGE(1);
    VM8;
    __builtin_amdgcn_s_barrier();

#pragma unroll 1
    for (int t = 0; t < NT; ++t) {
        if (t + 2 < NT)      TILE_BODY(t, G2_STAGE(t + 2), VM8);
        else if (t + 1 < NT) TILE_BODY(t, (void)0, VM0);
        else                 TILE_BODY(t, (void)0, (void)0);
    }
#undef G2_STAGE

#pragma unroll
    for (int am = 0; am < 8; ++am)
#pragma unroll
        for (int nt = 0; nt < 4; ++nt) {
            int n = blockIdx.x * 256 + wc * 64 + nt * 16 + lr;
            float bb = w0 * b2[e0 * D_ + n] + w1 * b2[e1 * D_ + n];
#pragma unroll
            for (int r = 0; r < 4; ++r) {
                int mrow = blockIdx.y * 256 + wr * 128 + (am >> 2) * 64 + (am & 3) * 16 + quad * 4 + r;
                out[((size_t)b * S_ + s0 + mrow) * D_ + n] = acc[am][nt][r] + bb;
            }
        }
}

// ===================== old 128x128 2-phase GEMMs (tier-C fallback only) =====================
template<int BT>
__global__ __launch_bounds__(256) void gemm1_kernel(
    const void* __restrict__ A_, const void* __restrict__ Bw_,
    const float* __restrict__ b1, const int* __restrict__ eidx,
    const float* __restrict__ wgate, u16* __restrict__ hbuf,
    int s0, int hRows, int pbase) {
    __shared__ __align__(16) u16 ldsA[1024 * 8];
    __shared__ __align__(16) u16 ldsB[1024 * 8];
    int tid = threadIdx.x, lane = tid & 63, wid = tid >> 6;
    int wm = wid & 1, wn = wid >> 1, lr = lane & 15, quad = lane >> 4;
    int lp = blockIdx.z, p = pbase + lp, b = p >> 1;
    int e = eidx[p];
    float wk = wgate[p];
    size_t arow = (size_t)(b * S_ + s0 + blockIdx.y * 128);
    floatx4 acc[4][4] = {};
    for (int kk = 0; kk < D_; kk += 64) {
        if (BT == 0) {
            stage((const u16*)A_ + arow * D_ + kk, D_, ldsA, tid);
            stage((const u16*)Bw_ + (size_t)e * H_ * D_ +
                  (size_t)(blockIdx.x * 128) * D_ + kk, D_, ldsB, tid);
        } else {
            stageF((const float*)A_ + arow * D_ + kk, D_, ldsA, tid);
            stageKTF((const float*)Bw_ + (size_t)e * D_ * H_ +
                     (size_t)kk * H_ + blockIdx.x * 128, H_, ldsB, tid);
        }
        __syncthreads();
#pragma unroll
        for (int ks = 0; ks < 2; ++ks) {
            bf16x8 af[4], bfr[4];
#pragma unroll
            for (int t = 0; t < 4; ++t) {
                af[t]  = fragld(ldsA, wm * 64 + t * 16 + lr, ks * 4 + quad);
                bfr[t] = fragld(ldsB, wn * 64 + t * 16 + lr, ks * 4 + quad);
            }
#pragma unroll
            for (int mt = 0; mt < 4; ++mt)
#pragma unroll
                for (int nt = 0; nt < 4; ++nt)
                    acc[mt][nt] = __builtin_amdgcn_mfma_f32_16x16x32_bf16(
                        af[mt], bfr[nt], acc[mt][nt], 0, 0, 0);
        }
        __syncthreads();
    }
#pragma unroll
    for (int mt = 0; mt < 4; ++mt)
#pragma unroll
        for (int nt = 0; nt < 4; ++nt) {
            int n = blockIdx.x * 128 + wn * 64 + nt * 16 + lr;
            float bb = b1[e * H_ + n];
#pragma unroll
            for (int r = 0; r < 4; ++r) {
                int mrow = blockIdx.y * 128 + wm * 64 + mt * 16 + quad * 4 + r;
                float v = acc[mt][nt][r] + bb;
                v = v / (1.f + __expf(-v)) * wk;
                hbuf[((size_t)lp * hRows + mrow) * H_ + n] = f2bf(v);
            }
        }
}

template<int BT>
__global__ __launch_bounds__(256) void gemm2_kernel(
    const u16* __restrict__ hbuf, const void* __restrict__ Bw_,
    const float* __restrict__ b2, const int* __restrict__ eidx,
    const float* __restrict__ wgate, float* __restrict__ out,
    int s0, int hRows, int bbase) {
    __shared__ __align__(16) u16 ldsA[1024 * 8];
    __shared__ __align__(16) u16 ldsB[1024 * 8];
    int tid = threadIdx.x, lane = tid & 63, wid = tid >> 6;
    int wm = wid & 1, wn = wid >> 1, lr = lane & 15, quad = lane >> 4;
    int lb = blockIdx.z, b = bbase + lb;
    floatx4 acc[4][4] = {};
    for (int kp = 0; kp < 2; ++kp) {
        int e = eidx[b * 2 + kp];
        const u16* Abase = hbuf + ((size_t)(lb * 2 + kp) * hRows + blockIdx.y * 128) * H_;
        for (int kk = 0; kk < H_; kk += 64) {
            stage(Abase + kk, H_, ldsA, tid);
            if (BT == 0)
                stage((const u16*)Bw_ + (size_t)e * D_ * H_ +
                      (size_t)(blockIdx.x * 128) * H_ + kk, H_, ldsB, tid);
            else
                stageKTF((const float*)Bw_ + (size_t)e * H_ * D_ +
                         (size_t)kk * D_ + blockIdx.x * 128, D_, ldsB, tid);
            __syncthreads();
#pragma unroll
            for (int ks = 0; ks < 2; ++ks) {
                bf16x8 af[4], bfr[4];
#pragma unroll
                for (int t = 0; t < 4; ++t) {
                    af[t]  = fragld(ldsA, wm * 64 + t * 16 + lr, ks * 4 + quad);
                    bfr[t] = fragld(ldsB, wn * 64 + t * 16 + lr, ks * 4 + quad);
                }
#pragma unroll
                for (int mt = 0; mt < 4; ++mt)
#pragma unroll
                    for (int nt = 0; nt < 4; ++nt)
                        acc[mt][nt] = __builtin_amdgcn_mfma_f32_16x16x32_bf16(
                            af[mt], bfr[nt], acc[mt][nt], 0, 0, 0);
            }
            __syncthreads();
        }
    }
    int e0 = eidx[b * 2], e1 = eidx[b * 2 + 1];
    float w0 = wgate[b * 2], w1 = wgate[b * 2 + 1];
#pragma unroll
    for (int mt = 0; mt < 4; ++mt)
#pragma unroll
        for (int nt = 0; nt < 4; ++nt) {
            int n = blockIdx.x * 128 + wn * 64 + nt * 16 + lr;
            float bb = w0 * b2[e0 * D_ + n] + w1 * b2[e1 * D_ + n];
#pragma unroll
            for (int r = 0; r < 4; ++r) {
                int mrow = blockIdx.y * 128 + wm * 64 + mt * 16 + quad * 4 + r;
                out[((size_t)b * S_ + s0 + mrow) * D_ + n] = acc[mt][nt][r] + bb;
            }
        }
}

extern "C" void kernel_launch(void* const* d_in, const int* in_sizes, int n_in,
                              void* d_out, int out_size, void* d_ws, size_t ws_size,
                              hipStream_t stream) {
    const float* x   = (const float*)d_in[0];
    const float* Wg1 = (const float*)d_in[1];
    const float* bg1 = (const float*)d_in[2];
    const float* Wg2 = (const float*)d_in[3];
    const float* bg2 = (const float*)d_in[4];
    const float* W1  = (const float*)d_in[5];
    const float* b1  = (const float*)d_in[6];
    const float* W2  = (const float*)d_in[7];
    const float* b2  = (const float*)d_in[8];
    float* out = (float*)d_out;
    char* ws = (char*)d_ws;

    float* ri    = (float*)ws;                 // 32 KB
    float* gh    = (float*)(ws + 32768);       // 32 KB
    float* wgate = (float*)(ws + 65536);       // 64 B
    int*   eidx  = (int*)(ws + 65792);         // 64 B
    float* part  = (float*)(ws + 131072);      // 256 KB mean partials

    const size_t base = (size_t)1 << 20;                  // 1 MiB small-buffer region
    const size_t szXb = (size_t)B_ * S_ * D_ * 2;         // 32 MiB bf16 x
    const size_t szW  = (size_t)E_ * D_ * H_ * 2;         // 64 MiB per bf16 weight set
    const size_t rowB = (size_t)H_ * 2;                   // 8 KiB per hbuf row

    mean1_kernel<<<dim3(B_ * 4, 8), 256, 0, stream>>>(x, part);
    mean2_kernel<<<dim3(B_ * 4), 256, 0, stream>>>(part, ri);
    gate1_kernel<<<dim3(B_ * 4), 256, 0, stream>>>(ri, Wg1, bg1, gh);
    gate2_kernel<<<1, 64, 0, stream>>>(gh, Wg2, bg2, wgate, eidx, out);

    auto clampSc256 = [](long v) -> int {
        long s = v & ~255L;
        if (s > S_) s = S_;
        if (s < 256) s = 256;
        return (int)s;
    };
    auto clampSc128 = [](long v) -> int {
        long s = v & ~127L;
        if (s > S_) s = S_;
        if (s < 128) s = 128;
        return (int)s;
    };

    if (ws_size >= base + szXb + 2 * szW + (size_t)16 * 256 * rowB) {
        // ---- Tier A: bf16 x + transposed bf16 weights + hbuf; 256x256 v2 GEMMs ----
        u16* xb   = (u16*)(ws + base);
        u16* W1T  = (u16*)(ws + base + szXb);
        u16* W2T  = (u16*)(ws + base + szXb + szW);
        u16* hbuf = (u16*)(ws + base + szXb + 2 * szW);
        int Sc = clampSc256((long)((ws_size - base - szXb - 2 * szW) / ((size_t)16 * rowB)));
        convx_kernel<<<dim3((B_ * S_ * D_) / (256 * 8)), 256, 0, stream>>>(x, xb);
        convT_kernel<<<dim3(H_ / 64, D_ / 64, E_), 256, 0, stream>>>(W1, W1T, D_, H_);
        convT_kernel<<<dim3(D_ / 64, H_ / 64, E_), 256, 0, stream>>>(W2, W2T, H_, D_);
        for (int s0 = 0; s0 < S_; s0 += Sc) {
            int rows = (S_ - s0 < Sc) ? (S_ - s0) : Sc;
            gemm1_v2<<<dim3(H_ / 256, rows / 256, B_ * 2), 512, 0, stream>>>(
                xb, W1T, b1, eidx, wgate, hbuf, s0, Sc);
            gemm2_v2<<<dim3(D_ / 256, rows / 256, B_), 512, 0, stream>>>(
                hbuf, W2T, b2, eidx, wgate, out, s0, Sc);
        }
    } else {
        // ---- Tier C: no conversion buffers; stage fp32->bf16 through LDS (old path) ----
        u16* hbuf = (u16*)(ws + base);
        long avail = (long)ws_size - (long)base;
        if (avail < 0) avail = 0;
        int Sc = clampSc128(avail / (long)(2 * rowB));
        for (int b = 0; b < B_; ++b) {
            for (int s0 = 0; s0 < S_; s0 += Sc) {
                int rows = (S_ - s0 < Sc) ? (S_ - s0) : Sc;
                gemm1_kernel<1><<<dim3(H_ / 128, rows / 128, 2), 256, 0, stream>>>(
                    x, W1, b1, eidx, wgate, hbuf, s0, Sc, b * 2);
                gemm2_kernel<1><<<dim3(D_ / 128, rows / 128, 1), 256, 0, stream>>>(
                    hbuf, W2, b2, eidx, wgate, out, s0, Sc, b);
            }
        }
    }
}

// Round 3
// 2271.026 us; speedup vs baseline: 1.2294x; 1.2294x over previous
//
#include <hip/hip_runtime.h>
#include <hip/hip_bf16.h>
#include <cstdint>
#include <cstddef>

typedef unsigned short u16;
typedef __attribute__((ext_vector_type(8))) __bf16 bf16x8;
typedef __attribute__((ext_vector_type(4))) float floatx4;

#define B_ 8
#define S_ 2048
#define D_ 1024
#define H_ 4096
#define E_ 8

__device__ __forceinline__ u16 f2bf(float f) {
    union { float f; unsigned u; } c; c.f = f;
    return (u16)((c.u + 0x7fffu + ((c.u >> 16) & 1u)) >> 16);  // RNE, finite inputs
}

__device__ __forceinline__ void gload16(const void* g, void* l) {
    __builtin_amdgcn_global_load_lds((__attribute__((address_space(1))) void*)(g),
                                     (__attribute__((address_space(3))) void*)(l),
                                     16, 0, 0);
}

// ---- LDS tile layout (proven m97-family swizzle; rows of 64 K = 128 B = 8 chunks of 16 B)
// Slot j holds (row r=j>>3, chunk c=(j&7)^(r&7)).  fragld(row, c) reads chunk c of row.
__device__ __forceinline__ bf16x8 fragld(const u16* lds, int row, int c) {
    return *(const bf16x8*)(lds + (((row << 3) + (c ^ (row & 7))) << 3));
}

// ===================== tier-C staging helpers (fallback path) =====================
__device__ __forceinline__ void stage(const u16* gbase, int ld, u16* lds, int tid) {
    int wid = tid >> 6;
#pragma unroll
    for (int q = 0; q < 4; ++q) {
        int j = q * 256 + tid;
        int r = j >> 3;
        int c = (j & 7) ^ (r & 7);
        gload16(gbase + (size_t)r * ld + c * 8,
                lds + (size_t)(q * 256 + wid * 64) * 8);
    }
}

__device__ __forceinline__ void stageF(const float* gbase, int ld, u16* lds, int tid) {
#pragma unroll
    for (int q = 0; q < 4; ++q) {
        int j = q * 256 + tid;
        int r = j >> 3;
        int c = (j & 7) ^ (r & 7);
        const float* src = gbase + (size_t)r * ld + c * 8;
        u16 tmp[8];
#pragma unroll
        for (int i = 0; i < 8; ++i) tmp[i] = f2bf(src[i]);
        *(uint4*)(lds + (size_t)j * 8) = *(uint4*)tmp;
    }
}

__device__ __forceinline__ void stageKTF(const float* gbase, int ld, u16* lds, int tid) {
#pragma unroll
    for (int q = 0; q < 4; ++q) {
        int g = q * 256 + tid;
        int k = g >> 4;
        int nc = g & 15;
        const float* src = gbase + (size_t)k * ld + nc * 8;
        int kc = k >> 3, kl = k & 7;
#pragma unroll
        for (int i = 0; i < 8; ++i) {
            int n = nc * 8 + i;
            lds[(((n << 3) + (kc ^ (n & 7))) << 3) + kl] = f2bf(src[i]);
        }
    }
}

// ---------------- gate (fp32 throughout) ----------------
__global__ void mean1_kernel(const float* __restrict__ x, float* __restrict__ part) {
    int d = (blockIdx.x & 3) * 256 + threadIdx.x;
    int b = blockIdx.x >> 2;
    int sc = blockIdx.y;
    const float* p = x + (size_t)b * S_ * D_ + (size_t)sc * 256 * D_ + d;
    float s = 0.f;
#pragma unroll 8
    for (int i = 0; i < 256; ++i) s += p[(size_t)i * D_];
    part[((size_t)b * 8 + sc) * D_ + d] = s;
}

__global__ void mean2_kernel(const float* __restrict__ part, float* __restrict__ ri) {
    int d = (blockIdx.x & 3) * 256 + threadIdx.x;
    int b = blockIdx.x >> 2;
    float s = 0.f;
#pragma unroll
    for (int i = 0; i < 8; ++i) s += part[((size_t)b * 8 + i) * D_ + d];
    ri[b * D_ + d] = s * (1.0f / S_);
}

__global__ void gate1_kernel(const float* __restrict__ ri, const float* __restrict__ Wg1,
                             const float* __restrict__ bg1, float* __restrict__ gh) {
    int j = (blockIdx.x & 3) * 256 + threadIdx.x;
    int b = blockIdx.x >> 2;
    const float* r = ri + b * D_;
    float acc = 0.f;
    for (int i = 0; i < D_; ++i) acc += r[i] * Wg1[(size_t)i * D_ + j];
    acc += bg1[j];
    gh[b * D_ + j] = acc / (1.f + expf(-acc));
}

__global__ void gate2_kernel(const float* __restrict__ gh, const float* __restrict__ Wg2,
                             const float* __restrict__ bg2, float* __restrict__ wgate,
                             int* __restrict__ eidx, float* __restrict__ out) {
    __shared__ float lg[B_ * E_];
    int t = threadIdx.x;  // 64 threads: (b,e) pairs
    int b = t >> 3, e = t & 7;
    const float* g = gh + b * D_;
    float acc = 0.f;
    for (int i = 0; i < D_; ++i) acc += g[i] * Wg2[(size_t)i * E_ + e];
    acc += bg2[e];
    lg[t] = acc;
    __syncthreads();
    if (t < B_) {
        float l0 = -1e30f, l1 = -1e30f; int i0 = 0, i1 = 0;
        for (int ee = 0; ee < E_; ++ee) {
            float v = lg[t * E_ + ee];
            if (v > l0) { l1 = l0; i1 = i0; l0 = v; i0 = ee; }
            else if (v > l1) { l1 = v; i1 = ee; }
        }
        float e1 = expf(l1 - l0);
        float w0 = 1.f / (1.f + e1), w1 = e1 / (1.f + e1);
        wgate[t * 2] = w0; wgate[t * 2 + 1] = w1;
        eidx[t * 2] = i0;  eidx[t * 2 + 1] = i1;
        float* ow = out + (size_t)B_ * S_ * D_;        // tail: topk_w then topk_idx
        ow[t * 2] = w0;              ow[t * 2 + 1] = w1;
        ow[16 + t * 2] = (float)i0;  ow[16 + t * 2 + 1] = (float)i1;
    }
}

// ---------------- converters (tier A) ----------------
__global__ void convx_kernel(const float* __restrict__ in, u16* __restrict__ out) {
    size_t i = ((size_t)blockIdx.x * 256 + threadIdx.x) * 8;
    u16 tmp[8];
#pragma unroll
    for (int j = 0; j < 8; ++j) tmp[j] = f2bf(in[i + j]);
    *(uint4*)(out + i) = *(uint4*)tmp;
}

// in fp32 [E][R][C] -> out bf16 [E][C][R]
__global__ __launch_bounds__(256) void convT_kernel(const float* __restrict__ in,
                                                    u16* __restrict__ out,
                                                    int R, int C) {
    __shared__ __align__(16) u16 T[64][72];
    int e = blockIdx.z;
    const float* ine = in + (size_t)e * R * C;
    u16* oute = out + (size_t)e * R * C;
    int r0 = blockIdx.y * 64, c0 = blockIdx.x * 64;
    int tid = threadIdx.x;
#pragma unroll
    for (int q = 0; q < 2; ++q) {
        int j = q * 256 + tid;
        int r = j >> 3, ch = j & 7;
        const float* src = ine + (size_t)(r0 + r) * C + c0 + ch * 8;
        u16 tmp[8];
#pragma unroll
        for (int i = 0; i < 8; ++i) tmp[i] = f2bf(src[i]);
        *(uint4*)&T[r][ch * 8] = *(uint4*)tmp;
    }
    __syncthreads();
#pragma unroll
    for (int q = 0; q < 2; ++q) {
        int j = q * 256 + tid;
        int orow = j >> 3, och = j & 7;
        uint4 v; u16* pv = (u16*)&v;
#pragma unroll
        for (int i = 0; i < 8; ++i) pv[i] = T[och * 8 + i][orow];
        *(uint4*)(oute + (size_t)(c0 + orow) * R + r0 + och * 8) = v;
    }
}

// ===================== 256x256 free-running GEMMs (tier A) =====================
// BK=64, double-buffered (2x 32KB A + 2x 32KB B = 128 KiB LDS), 8 waves (2M x 4N),
// per-wave C = 128x64 (acc[8][4]).  Per 64-K tile: 24 ds_read_b128 + 64 MFMA.
// Live fragment set kept small (8 B-frags + 2 A-frags) to avoid VGPR spill (r2 lesson).
// 2 barriers per tile (asm s_barrier = also a compiler memory fence):
//   #1 after LG0 (all this-wave reads done; barrier -> all waves done)
//      -> safe to stage tile t+2 into the buffer tile t occupied.
//   #2 after per-wave vmcnt(8) -> tile t+1's data (from ALL waves) landed.
// vmcnt never drains to 0 in steady state (counted, T4).

#define VM8  asm volatile("s_waitcnt vmcnt(8)" ::: "memory")
#define VM0  asm volatile("s_waitcnt vmcnt(0)" ::: "memory")
#define LG0  asm volatile("s_waitcnt lgkmcnt(0)" ::: "memory")
#define BARRIER asm volatile("s_barrier" ::: "memory")

// per-thread setup shared by both v3 kernels; LDB = row stride in bytes
#define SETUP_V3(LDB) \
    const int tid = threadIdx.x, lane = tid & 63, wid = tid >> 6; \
    const int wr = wid >> 2, wc = wid & 3, lr = lane & 15, quad = lane >> 4; \
    int goff[4], dstg[4]; \
    _Pragma("unroll") for (int q = 0; q < 4; ++q) { \
        int j = q * 512 + tid, r = j >> 3, c = (j & 7) ^ (r & 7); \
        goff[q] = r * (LDB) + c * 16; \
        dstg[q] = (q * 512 + wid * 64) * 8; \
    } \
    floatx4 acc[8][4] = {};

// tile-t compute: B frags once (32 regs), then 8 A-subtiles x {2 A-frags, 8 MFMA}
#define TILE_BODY(T, STAGE_STMT, VM_STMT) do { \
    const u16* sA = lA[(T) & 1]; \
    const u16* sB = lB[(T) & 1]; \
    bf16x8 bfv[4][2]; \
    _Pragma("unroll") for (int nt = 0; nt < 4; ++nt) \
        _Pragma("unroll") for (int ks = 0; ks < 2; ++ks) \
            bfv[nt][ks] = fragld(sB, wc * 64 + nt * 16 + lr, ks * 4 + quad); \
    _Pragma("unroll") for (int am = 0; am < 8; ++am) { \
        int arow = wr * 128 + (am >> 2) * 64 + (am & 3) * 16 + lr; \
        bf16x8 a0 = fragld(sA, arow, quad); \
        bf16x8 a1 = fragld(sA, arow, 4 + quad); \
        _Pragma("unroll") for (int nt = 0; nt < 4; ++nt) { \
            acc[am][nt] = __builtin_amdgcn_mfma_f32_16x16x32_bf16(a0, bfv[nt][0], acc[am][nt], 0, 0, 0); \
            acc[am][nt] = __builtin_amdgcn_mfma_f32_16x16x32_bf16(a1, bfv[nt][1], acc[am][nt], 0, 0, 0); \
        } \
    } \
    LG0; \
    BARRIER;  /* #1 */ \
    STAGE_STMT; \
    VM_STMT; \
    BARRIER;  /* #2 */ \
} while (0)

// GEMM1: hbuf[lp] = wk * silu(xb[b] @ W1T[e]^T + b1[e]); A,B row-major k-contig, ld=D_
__global__ __launch_bounds__(512) void gemm1_v3(
    const u16* __restrict__ A, const u16* __restrict__ Bw,
    const float* __restrict__ b1, const int* __restrict__ eidx,
    const float* __restrict__ wgate, u16* __restrict__ hbuf,
    int s0, int hRows) {
    __shared__ __align__(16) u16 lA[2][16384];
    __shared__ __align__(16) u16 lB[2][16384];
    SETUP_V3(D_ * 2)
    const int lp = blockIdx.z, b = lp >> 1;
    const int e = eidx[lp];
    const float wk = wgate[lp];
    const char* Ab = (const char*)(A + (size_t)(b * S_ + s0 + blockIdx.y * 256) * D_);
    const char* Bb = (const char*)(Bw + (size_t)e * H_ * D_ + (size_t)(blockIdx.x * 256) * D_);
    const int NT = D_ / 64;  // 16

#define G1_STAGE(T) do { const int kb = (T) * 128, bi = (T) & 1; \
        _Pragma("unroll") for (int q = 0; q < 4; ++q) gload16(Ab + goff[q] + kb, &lA[bi][dstg[q]]); \
        _Pragma("unroll") for (int q = 0; q < 4; ++q) gload16(Bb + goff[q] + kb, &lB[bi][dstg[q]]); \
    } while (0)

    G1_STAGE(0); G1_STAGE(1);
    VM8;
    BARRIER;

#pragma unroll 1
    for (int t = 0; t < NT; ++t) {
        if (t + 2 < NT)      TILE_BODY(t, G1_STAGE(t + 2), VM8);
        else if (t + 1 < NT) TILE_BODY(t, (void)0, VM0);
        else                 TILE_BODY(t, (void)0, (void)0);
    }
#undef G1_STAGE

#pragma unroll
    for (int am = 0; am < 8; ++am)
#pragma unroll
        for (int nt = 0; nt < 4; ++nt) {
            int n = blockIdx.x * 256 + wc * 64 + nt * 16 + lr;
            float bb = b1[e * H_ + n];
#pragma unroll
            for (int r = 0; r < 4; ++r) {
                int mrow = blockIdx.y * 256 + wr * 128 + (am >> 2) * 64 + (am & 3) * 16 + quad * 4 + r;
                float v = acc[am][nt][r] + bb;
                v = v / (1.f + __expf(-v)) * wk;
                hbuf[((size_t)lp * hRows + mrow) * H_ + n] = f2bf(v);
            }
        }
}

// GEMM2: out[b] = sum_kp hbuf[b*2+kp] @ W2T[e_kp]^T + sum w*b2; virtual K = 2*H_, ld=H_
__global__ __launch_bounds__(512) void gemm2_v3(
    const u16* __restrict__ hbuf, const u16* __restrict__ Bw,
    const float* __restrict__ b2, const int* __restrict__ eidx,
    const float* __restrict__ wgate, float* __restrict__ out,
    int s0, int hRows) {
    __shared__ __align__(16) u16 lA[2][16384];
    __shared__ __align__(16) u16 lB[2][16384];
    SETUP_V3(H_ * 2)
    const int b = blockIdx.z;
    const int e0 = eidx[b * 2], e1 = eidx[b * 2 + 1];
    const float w0 = wgate[b * 2], w1 = wgate[b * 2 + 1];
    const char* Ab0 = (const char*)(hbuf + ((size_t)(b * 2) * hRows + blockIdx.y * 256) * H_);
    const char* Ab1 = (const char*)(hbuf + ((size_t)(b * 2 + 1) * hRows + blockIdx.y * 256) * H_);
    const char* Bb0 = (const char*)(Bw + (size_t)e0 * D_ * H_ + (size_t)(blockIdx.x * 256) * H_);
    const char* Bb1 = (const char*)(Bw + (size_t)e1 * D_ * H_ + (size_t)(blockIdx.x * 256) * H_);
    const int NT = 2 * H_ / 64;  // 128

#define G2_STAGE(T) do { const int tt = (T); const int kb = (tt & 63) * 128, bi = tt & 1; \
        const char* As_ = (tt & 64) ? Ab1 : Ab0; \
        const char* Bs_ = (tt & 64) ? Bb1 : Bb0; \
        _Pragma("unroll") for (int q = 0; q < 4; ++q) gload16(As_ + goff[q] + kb, &lA[bi][dstg[q]]); \
        _Pragma("unroll") for (int q = 0; q < 4; ++q) gload16(Bs_ + goff[q] + kb, &lB[bi][dstg[q]]); \
    } while (0)

    G2_STAGE(0); G2_STAGE(1);
    VM8;
    BARRIER;

#pragma unroll 1
    for (int t = 0; t < NT; ++t) {
        if (t + 2 < NT)      TILE_BODY(t, G2_STAGE(t + 2), VM8);
        else if (t + 1 < NT) TILE_BODY(t, (void)0, VM0);
        else                 TILE_BODY(t, (void)0, (void)0);
    }
#undef G2_STAGE

#pragma unroll
    for (int am = 0; am < 8; ++am)
#pragma unroll
        for (int nt = 0; nt < 4; ++nt) {
            int n = blockIdx.x * 256 + wc * 64 + nt * 16 + lr;
            float bb = w0 * b2[e0 * D_ + n] + w1 * b2[e1 * D_ + n];
#pragma unroll
            for (int r = 0; r < 4; ++r) {
                int mrow = blockIdx.y * 256 + wr * 128 + (am >> 2) * 64 + (am & 3) * 16 + quad * 4 + r;
                out[((size_t)b * S_ + s0 + mrow) * D_ + n] = acc[am][nt][r] + bb;
            }
        }
}

// ===================== old 128x128 2-phase GEMMs (tier-C fallback only) =====================
template<int BT>
__global__ __launch_bounds__(256) void gemm1_kernel(
    const void* __restrict__ A_, const void* __restrict__ Bw_,
    const float* __restrict__ b1, const int* __restrict__ eidx,
    const float* __restrict__ wgate, u16* __restrict__ hbuf,
    int s0, int hRows, int pbase) {
    __shared__ __align__(16) u16 ldsA[1024 * 8];
    __shared__ __align__(16) u16 ldsB[1024 * 8];
    int tid = threadIdx.x, lane = tid & 63, wid = tid >> 6;
    int wm = wid & 1, wn = wid >> 1, lr = lane & 15, quad = lane >> 4;
    int lp = blockIdx.z, p = pbase + lp, b = p >> 1;
    int e = eidx[p];
    float wk = wgate[p];
    size_t arow = (size_t)(b * S_ + s0 + blockIdx.y * 128);
    floatx4 acc[4][4] = {};
    for (int kk = 0; kk < D_; kk += 64) {
        if (BT == 0) {
            stage((const u16*)A_ + arow * D_ + kk, D_, ldsA, tid);
            stage((const u16*)Bw_ + (size_t)e * H_ * D_ +
                  (size_t)(blockIdx.x * 128) * D_ + kk, D_, ldsB, tid);
        } else {
            stageF((const float*)A_ + arow * D_ + kk, D_, ldsA, tid);
            stageKTF((const float*)Bw_ + (size_t)e * D_ * H_ +
                     (size_t)kk * H_ + blockIdx.x * 128, H_, ldsB, tid);
        }
        __syncthreads();
#pragma unroll
        for (int ks = 0; ks < 2; ++ks) {
            bf16x8 af[4], bfr[4];
#pragma unroll
            for (int t = 0; t < 4; ++t) {
                af[t]  = fragld(ldsA, wm * 64 + t * 16 + lr, ks * 4 + quad);
                bfr[t] = fragld(ldsB, wn * 64 + t * 16 + lr, ks * 4 + quad);
            }
#pragma unroll
            for (int mt = 0; mt < 4; ++mt)
#pragma unroll
                for (int nt = 0; nt < 4; ++nt)
                    acc[mt][nt] = __builtin_amdgcn_mfma_f32_16x16x32_bf16(
                        af[mt], bfr[nt], acc[mt][nt], 0, 0, 0);
        }
        __syncthreads();
    }
#pragma unroll
    for (int mt = 0; mt < 4; ++mt)
#pragma unroll
        for (int nt = 0; nt < 4; ++nt) {
            int n = blockIdx.x * 128 + wn * 64 + nt * 16 + lr;
            float bb = b1[e * H_ + n];
#pragma unroll
            for (int r = 0; r < 4; ++r) {
                int mrow = blockIdx.y * 128 + wm * 64 + mt * 16 + quad * 4 + r;
                float v = acc[mt][nt][r] + bb;
                v = v / (1.f + __expf(-v)) * wk;
                hbuf[((size_t)lp * hRows + mrow) * H_ + n] = f2bf(v);
            }
        }
}

template<int BT>
__global__ __launch_bounds__(256) void gemm2_kernel(
    const u16* __restrict__ hbuf, const void* __restrict__ Bw_,
    const float* __restrict__ b2, const int* __restrict__ eidx,
    const float* __restrict__ wgate, float* __restrict__ out,
    int s0, int hRows, int bbase) {
    __shared__ __align__(16) u16 ldsA[1024 * 8];
    __shared__ __align__(16) u16 ldsB[1024 * 8];
    int tid = threadIdx.x, lane = tid & 63, wid = tid >> 6;
    int wm = wid & 1, wn = wid >> 1, lr = lane & 15, quad = lane >> 4;
    int lb = blockIdx.z, b = bbase + lb;
    floatx4 acc[4][4] = {};
    for (int kp = 0; kp < 2; ++kp) {
        int e = eidx[b * 2 + kp];
        const u16* Abase = hbuf + ((size_t)(lb * 2 + kp) * hRows + blockIdx.y * 128) * H_;
        for (int kk = 0; kk < H_; kk += 64) {
            stage(Abase + kk, H_, ldsA, tid);
            if (BT == 0)
                stage((const u16*)Bw_ + (size_t)e * D_ * H_ +
                      (size_t)(blockIdx.x * 128) * H_ + kk, H_, ldsB, tid);
            else
                stageKTF((const float*)Bw_ + (size_t)e * H_ * D_ +
                         (size_t)kk * D_ + blockIdx.x * 128, D_, ldsB, tid);
            __syncthreads();
#pragma unroll
            for (int ks = 0; ks < 2; ++ks) {
                bf16x8 af[4], bfr[4];
#pragma unroll
                for (int t = 0; t < 4; ++t) {
                    af[t]  = fragld(ldsA, wm * 64 + t * 16 + lr, ks * 4 + quad);
                    bfr[t] = fragld(ldsB, wn * 64 + t * 16 + lr, ks * 4 + quad);
                }
#pragma unroll
                for (int mt = 0; mt < 4; ++mt)
#pragma unroll
                    for (int nt = 0; nt < 4; ++nt)
                        acc[mt][nt] = __builtin_amdgcn_mfma_f32_16x16x32_bf16(
                            af[mt], bfr[nt], acc[mt][nt], 0, 0, 0);
            }
            __syncthreads();
        }
    }
    int e0 = eidx[b * 2], e1 = eidx[b * 2 + 1];
    float w0 = wgate[b * 2], w1 = wgate[b * 2 + 1];
#pragma unroll
    for (int mt = 0; mt < 4; ++mt)
#pragma unroll
        for (int nt = 0; nt < 4; ++nt) {
            int n = blockIdx.x * 128 + wn * 64 + nt * 16 + lr;
            float bb = w0 * b2[e0 * D_ + n] + w1 * b2[e1 * D_ + n];
#pragma unroll
            for (int r = 0; r < 4; ++r) {
                int mrow = blockIdx.y * 128 + wm * 64 + mt * 16 + quad * 4 + r;
                out[((size_t)b * S_ + s0 + mrow) * D_ + n] = acc[mt][nt][r] + bb;
            }
        }
}

extern "C" void kernel_launch(void* const* d_in, const int* in_sizes, int n_in,
                              void* d_out, int out_size, void* d_ws, size_t ws_size,
                              hipStream_t stream) {
    const float* x   = (const float*)d_in[0];
    const float* Wg1 = (const float*)d_in[1];
    const float* bg1 = (const float*)d_in[2];
    const float* Wg2 = (const float*)d_in[3];
    const float* bg2 = (const float*)d_in[4];
    const float* W1  = (const float*)d_in[5];
    const float* b1  = (const float*)d_in[6];
    const float* W2  = (const float*)d_in[7];
    const float* b2  = (const float*)d_in[8];
    float* out = (float*)d_out;
    char* ws = (char*)d_ws;

    float* ri    = (float*)ws;                 // 32 KB
    float* gh    = (float*)(ws + 32768);       // 32 KB
    float* wgate = (float*)(ws + 65536);       // 64 B
    int*   eidx  = (int*)(ws + 65792);         // 64 B
    float* part  = (float*)(ws + 131072);      // 256 KB mean partials

    const size_t base = (size_t)1 << 20;                  // 1 MiB small-buffer region
    const size_t szXb = (size_t)B_ * S_ * D_ * 2;         // 32 MiB bf16 x
    const size_t szW  = (size_t)E_ * D_ * H_ * 2;         // 64 MiB per bf16 weight set
    const size_t rowB = (size_t)H_ * 2;                   // 8 KiB per hbuf row

    mean1_kernel<<<dim3(B_ * 4, 8), 256, 0, stream>>>(x, part);
    mean2_kernel<<<dim3(B_ * 4), 256, 0, stream>>>(part, ri);
    gate1_kernel<<<dim3(B_ * 4), 256, 0, stream>>>(ri, Wg1, bg1, gh);
    gate2_kernel<<<1, 64, 0, stream>>>(gh, Wg2, bg2, wgate, eidx, out);

    auto clampSc256 = [](long v) -> int {
        long s = v & ~255L;
        if (s > S_) s = S_;
        if (s < 256) s = 256;
        return (int)s;
    };
    auto clampSc128 = [](long v) -> int {
        long s = v & ~127L;
        if (s > S_) s = S_;
        if (s < 128) s = 128;
        return (int)s;
    };

    if (ws_size >= base + szXb + 2 * szW + (size_t)16 * 256 * rowB) {
        // ---- Tier A: bf16 x + transposed bf16 weights + hbuf; 256x256 v3 GEMMs ----
        u16* xb   = (u16*)(ws + base);
        u16* W1T  = (u16*)(ws + base + szXb);
        u16* W2T  = (u16*)(ws + base + szXb + szW);
        u16* hbuf = (u16*)(ws + base + szXb + 2 * szW);
        int Sc = clampSc256((long)((ws_size - base - szXb - 2 * szW) / ((size_t)16 * rowB)));
        convx_kernel<<<dim3((B_ * S_ * D_) / (256 * 8)), 256, 0, stream>>>(x, xb);
        convT_kernel<<<dim3(H_ / 64, D_ / 64, E_), 256, 0, stream>>>(W1, W1T, D_, H_);
        convT_kernel<<<dim3(D_ / 64, H_ / 64, E_), 256, 0, stream>>>(W2, W2T, H_, D_);
        for (int s0 = 0; s0 < S_; s0 += Sc) {
            int rows = (S_ - s0 < Sc) ? (S_ - s0) : Sc;
            gemm1_v3<<<dim3(H_ / 256, rows / 256, B_ * 2), 512, 0, stream>>>(
                xb, W1T, b1, eidx, wgate, hbuf, s0, Sc);
            gemm2_v3<<<dim3(D_ / 256, rows / 256, B_), 512, 0, stream>>>(
                hbuf, W2T, b2, eidx, wgate, out, s0, Sc);
        }
    } else {
        // ---- Tier C: no conversion buffers; stage fp32->bf16 through LDS (old path) ----
        u16* hbuf = (u16*)(ws + base);
        long avail = (long)ws_size - (long)base;
        if (avail < 0) avail = 0;
        int Sc = clampSc128(avail / (long)(2 * rowB));
        for (int b = 0; b < B_; ++b) {
            for (int s0 = 0; s0 < S_; s0 += Sc) {
                int rows = (S_ - s0 < Sc) ? (S_ - s0) : Sc;
                gemm1_kernel<1><<<dim3(H_ / 128, rows / 128, 2), 256, 0, stream>>>(
                    x, W1, b1, eidx, wgate, hbuf, s0, Sc, b * 2);
                gemm2_kernel<1><<<dim3(D_ / 128, rows / 128, 1), 256, 0, stream>>>(
                    hbuf, W2, b2, eidx, wgate, out, s0, Sc, b);
            }
        }
    }
}

// Round 4
// 1006.021 us; speedup vs baseline: 2.7753x; 2.2574x over previous
//
#include <hip/hip_runtime.h>
#include <hip/hip_bf16.h>
#include <cstdint>
#include <cstddef>

typedef unsigned short u16;
typedef __attribute__((ext_vector_type(8))) __bf16 bf16x8;
typedef __attribute__((ext_vector_type(4))) float floatx4;

#define B_ 8
#define S_ 2048
#define D_ 1024
#define H_ 4096
#define E_ 8

__device__ __forceinline__ u16 f2bf(float f) {
    union { float f; unsigned u; } c; c.f = f;
    return (u16)((c.u + 0x7fffu + ((c.u >> 16) & 1u)) >> 16);  // RNE, finite inputs
}

__device__ __forceinline__ void gload16(const void* g, void* l) {
    __builtin_amdgcn_global_load_lds((__attribute__((address_space(1))) void*)(g),
                                     (__attribute__((address_space(3))) void*)(l),
                                     16, 0, 0);
}

// ---- LDS half-tile layout (proven r0 swizzle): 128 rows x 64 K (128 B = 8 chunks/row).
// Slot j holds (row r=j>>3, chunk c=(j&7)^(r&7)); staged linearly, source pre-swizzled.
__device__ __forceinline__ bf16x8 fragld(const u16* lds, int row, int c) {
    return *(const bf16x8*)(lds + (((row << 3) + (c ^ (row & 7))) << 3));
}

// ===================== tier-C staging helpers (fallback path) =====================
__device__ __forceinline__ void stage(const u16* gbase, int ld, u16* lds, int tid) {
    int wid = tid >> 6;
#pragma unroll
    for (int q = 0; q < 4; ++q) {
        int j = q * 256 + tid;
        int r = j >> 3;
        int c = (j & 7) ^ (r & 7);
        gload16(gbase + (size_t)r * ld + c * 8,
                lds + (size_t)(q * 256 + wid * 64) * 8);
    }
}

__device__ __forceinline__ void stageF(const float* gbase, int ld, u16* lds, int tid) {
#pragma unroll
    for (int q = 0; q < 4; ++q) {
        int j = q * 256 + tid;
        int r = j >> 3;
        int c = (j & 7) ^ (r & 7);
        const float* src = gbase + (size_t)r * ld + c * 8;
        u16 tmp[8];
#pragma unroll
        for (int i = 0; i < 8; ++i) tmp[i] = f2bf(src[i]);
        *(uint4*)(lds + (size_t)j * 8) = *(uint4*)tmp;
    }
}

__device__ __forceinline__ void stageKTF(const float* gbase, int ld, u16* lds, int tid) {
#pragma unroll
    for (int q = 0; q < 4; ++q) {
        int g = q * 256 + tid;
        int k = g >> 4;
        int nc = g & 15;
        const float* src = gbase + (size_t)k * ld + nc * 8;
        int kc = k >> 3, kl = k & 7;
#pragma unroll
        for (int i = 0; i < 8; ++i) {
            int n = nc * 8 + i;
            lds[(((n << 3) + (kc ^ (n & 7))) << 3) + kl] = f2bf(src[i]);
        }
    }
}

// ---------------- gate (fp32 throughout) ----------------
__global__ void mean1_kernel(const float* __restrict__ x, float* __restrict__ part) {
    int d = (blockIdx.x & 3) * 256 + threadIdx.x;
    int b = blockIdx.x >> 2;
    int sc = blockIdx.y;
    const float* p = x + (size_t)b * S_ * D_ + (size_t)sc * 256 * D_ + d;
    float s = 0.f;
#pragma unroll 8
    for (int i = 0; i < 256; ++i) s += p[(size_t)i * D_];
    part[((size_t)b * 8 + sc) * D_ + d] = s;
}

__global__ void mean2_kernel(const float* __restrict__ part, float* __restrict__ ri) {
    int d = (blockIdx.x & 3) * 256 + threadIdx.x;
    int b = blockIdx.x >> 2;
    float s = 0.f;
#pragma unroll
    for (int i = 0; i < 8; ++i) s += part[((size_t)b * 8 + i) * D_ + d];
    ri[b * D_ + d] = s * (1.0f / S_);
}

__global__ void gate1_kernel(const float* __restrict__ ri, const float* __restrict__ Wg1,
                             const float* __restrict__ bg1, float* __restrict__ gh) {
    int j = (blockIdx.x & 3) * 256 + threadIdx.x;
    int b = blockIdx.x >> 2;
    const float* r = ri + b * D_;
    float acc = 0.f;
    for (int i = 0; i < D_; ++i) acc += r[i] * Wg1[(size_t)i * D_ + j];
    acc += bg1[j];
    gh[b * D_ + j] = acc / (1.f + expf(-acc));
}

__global__ void gate2_kernel(const float* __restrict__ gh, const float* __restrict__ Wg2,
                             const float* __restrict__ bg2, float* __restrict__ wgate,
                             int* __restrict__ eidx, float* __restrict__ out) {
    __shared__ float lg[B_ * E_];
    int t = threadIdx.x;  // 64 threads: (b,e) pairs
    int b = t >> 3, e = t & 7;
    const float* g = gh + b * D_;
    float acc = 0.f;
    for (int i = 0; i < D_; ++i) acc += g[i] * Wg2[(size_t)i * E_ + e];
    acc += bg2[e];
    lg[t] = acc;
    __syncthreads();
    if (t < B_) {
        float l0 = -1e30f, l1 = -1e30f; int i0 = 0, i1 = 0;
        for (int ee = 0; ee < E_; ++ee) {
            float v = lg[t * E_ + ee];
            if (v > l0) { l1 = l0; i1 = i0; l0 = v; i0 = ee; }
            else if (v > l1) { l1 = v; i1 = ee; }
        }
        float e1 = expf(l1 - l0);
        float w0 = 1.f / (1.f + e1), w1 = e1 / (1.f + e1);
        wgate[t * 2] = w0; wgate[t * 2 + 1] = w1;
        eidx[t * 2] = i0;  eidx[t * 2 + 1] = i1;
        float* ow = out + (size_t)B_ * S_ * D_;        // tail: topk_w then topk_idx
        ow[t * 2] = w0;              ow[t * 2 + 1] = w1;
        ow[16 + t * 2] = (float)i0;  ow[16 + t * 2 + 1] = (float)i1;
    }
}

// ---------------- converters (tier A) ----------------
__global__ void convx_kernel(const float* __restrict__ in, u16* __restrict__ out) {
    size_t i = ((size_t)blockIdx.x * 256 + threadIdx.x) * 8;
    u16 tmp[8];
#pragma unroll
    for (int j = 0; j < 8; ++j) tmp[j] = f2bf(in[i + j]);
    *(uint4*)(out + i) = *(uint4*)tmp;
}

// in fp32 [E][R][C] -> out bf16 [E][C][R]
__global__ __launch_bounds__(256) void convT_kernel(const float* __restrict__ in,
                                                    u16* __restrict__ out,
                                                    int R, int C) {
    __shared__ __align__(16) u16 T[64][72];
    int e = blockIdx.z;
    const float* ine = in + (size_t)e * R * C;
    u16* oute = out + (size_t)e * R * C;
    int r0 = blockIdx.y * 64, c0 = blockIdx.x * 64;
    int tid = threadIdx.x;
#pragma unroll
    for (int q = 0; q < 2; ++q) {
        int j = q * 256 + tid;
        int r = j >> 3, ch = j & 7;
        const float* src = ine + (size_t)(r0 + r) * C + c0 + ch * 8;
        u16 tmp[8];
#pragma unroll
        for (int i = 0; i < 8; ++i) tmp[i] = f2bf(src[i]);
        *(uint4*)&T[r][ch * 8] = *(uint4*)tmp;
    }
    __syncthreads();
#pragma unroll
    for (int q = 0; q < 2; ++q) {
        int j = q * 256 + tid;
        int orow = j >> 3, och = j & 7;
        uint4 v; u16* pv = (u16*)&v;
#pragma unroll
        for (int i = 0; i < 8; ++i) pv[i] = T[och * 8 + i][orow];
        *(uint4*)(oute + (size_t)(c0 + orow) * R + r0 + och * 8) = v;
    }
}

// ===================== 256x256 8-phase GEMMs, m201-faithful (tier A) =====================
// BK=64, 2 K-tiles per iter (buf0=even tile, buf1=odd tile), 8 phases/iter.
// LDS: lA[2][2][16KB] + lB[2][2][16KB] = 128 KiB. 8 waves (2M x 4N), per-wave C 128x64,
// quadrant (mh,nh) maps to LDS halves -> halves free early:
//   reads: ph1:(A0,B0) ph2:(B1) ph3:(A1) ph4:- (A held 2 phases, B held whole tile)
// stage 1 half/phase (2 gloads/thread): ph1:b1.A1(t+1) ph2:b1.B1(t+1) ph3:b0.A0(t+2)
//   ph4:b0.B0(t+2) ph5:b0.A1(t+2) ph6:b0.B1(t+2) ph7:b1.A0(t+3) ph8:b1.B0(t+3)
// counted vmcnt(4) ONLY at ph4/ph8 (max 12 loads in flight, never drain to 0 in steady
// state); coverage verified: every half lands >=1 barrier before its first read.

#define VM4  asm volatile("s_waitcnt vmcnt(4)" ::: "memory")
#define VM0  asm volatile("s_waitcnt vmcnt(0)" ::: "memory")
#define LG0  asm volatile("s_waitcnt lgkmcnt(0)" ::: "memory")
#define BARRIER asm volatile("s_barrier" ::: "memory")

#define RD_A(BI, MH) do { _Pragma("unroll") for (int t_ = 0; t_ < 4; ++t_) { \
    fa[t_*2+0] = fragld(&lA[BI][MH][0], wr*64 + t_*16 + lr, quad); \
    fa[t_*2+1] = fragld(&lA[BI][MH][0], wr*64 + t_*16 + lr, 4 + quad); } } while (0)

#define RD_B(BI, NH) do { _Pragma("unroll") for (int n_ = 0; n_ < 2; ++n_) { \
    fb[(NH)*4+n_*2+0] = fragld(&lB[BI][NH][0], wc*32 + n_*16 + lr, quad); \
    fb[(NH)*4+n_*2+1] = fragld(&lB[BI][NH][0], wc*32 + n_*16 + lr, 4 + quad); } } while (0)

#define MM(MH, NH) do { _Pragma("unroll") for (int t_ = 0; t_ < 4; ++t_) \
    _Pragma("unroll") for (int n_ = 0; n_ < 2; ++n_) \
    _Pragma("unroll") for (int k_ = 0; k_ < 2; ++k_) \
        acc[(MH)*4+t_][(NH)*2+n_] = __builtin_amdgcn_mfma_f32_16x16x32_bf16( \
            fa[t_*2+k_], fb[(NH)*4+n_*2+k_], acc[(MH)*4+t_][(NH)*2+n_], 0, 0, 0); } while (0)

// stage one 16 KB half: SRCX = char* base of the half (incl. k-offset), DSTP = lds half
#define STG(SRCX, DSTP) do { \
    gload16((SRCX) + gro0, (char*)(DSTP) + dst0); \
    gload16((SRCX) + gro0 + grostep, (char*)(DSTP) + dst1); } while (0)

#define PHASE(RD_STMT, STG_STMT, MH, NH, VM_STMT) do { \
    RD_STMT; \
    STG_STMT; \
    BARRIER; \
    LG0; \
    __builtin_amdgcn_s_setprio(1); \
    MM(MH, NH); \
    __builtin_amdgcn_s_setprio(0); \
    VM_STMT; \
    BARRIER; \
} while (0)

// common per-thread setup (LDBYC = row stride in bytes)
#define SETUP_V4(LDBYC) \
    const int tid = threadIdx.x, lane = tid & 63, wid = tid >> 6; \
    const int wr = wid >> 2, wc = wid & 3, lr = lane & 15, quad = lane >> 4; \
    const int LDBY = (LDBYC); \
    const int r_ = tid >> 3; \
    const int gro0 = r_ * LDBY + (((tid & 7) ^ (r_ & 7)) * 16); \
    const int grostep = 64 * LDBY; \
    const int dst0 = tid * 16, dst1 = dst0 + 8192; \
    bf16x8 fa[8], fb[8]; \
    floatx4 acc[8][4] = {};

#define EIGHT_PHASES(SA, SB, T0, LASTI) do { \
    PHASE(RD_A(0,0); RD_B(0,0), STG(SA((T0)+1,1), &lA[1][1][0]), 0, 0, (void)0); \
    PHASE(RD_B(0,1),            STG(SB((T0)+1,1), &lB[1][1][0]), 0, 1, (void)0); \
    if (!(LASTI)) { \
        PHASE(RD_A(0,1),            STG(SA((T0)+2,0), &lA[0][0][0]), 1, 0, (void)0); \
        PHASE((void)0,              STG(SB((T0)+2,0), &lB[0][0][0]), 1, 1, VM4); \
        PHASE(RD_A(1,0); RD_B(1,0), STG(SA((T0)+2,1), &lA[0][1][0]), 0, 0, (void)0); \
        PHASE(RD_B(1,1),            STG(SB((T0)+2,1), &lB[0][1][0]), 0, 1, (void)0); \
        PHASE(RD_A(1,1),            STG(SA((T0)+3,0), &lA[1][0][0]), 1, 0, (void)0); \
        PHASE((void)0,              STG(SB((T0)+3,0), &lB[1][0][0]), 1, 1, VM4); \
    } else { \
        PHASE(RD_A(0,1),            (void)0, 1, 0, (void)0); \
        PHASE((void)0,              (void)0, 1, 1, VM0); \
        PHASE(RD_A(1,0); RD_B(1,0), (void)0, 0, 0, (void)0); \
        PHASE(RD_B(1,1),            (void)0, 0, 1, (void)0); \
        PHASE(RD_A(1,1),            (void)0, 1, 0, (void)0); \
        PHASE((void)0,              (void)0, 1, 1, (void)0); \
    } \
} while (0)

// GEMM1: hbuf[lp] = wk * silu(xb[b] @ W1T[e]^T + b1[e]); A,B row-major k-contig, ld=D_
__global__ __launch_bounds__(512) void gemm1_v4(
    const u16* __restrict__ A, const u16* __restrict__ Bw,
    const float* __restrict__ b1, const int* __restrict__ eidx,
    const float* __restrict__ wgate, u16* __restrict__ hbuf,
    int s0, int hRows) {
    __shared__ __align__(16) u16 lA[2][2][8192];
    __shared__ __align__(16) u16 lB[2][2][8192];
    SETUP_V4(D_ * 2)
    const int lp = blockIdx.z, bb_ = lp >> 1;
    const int e = eidx[lp];
    const float wk = wgate[lp];
    const char* Ab = (const char*)(A + (size_t)(bb_ * S_ + s0 + blockIdx.y * 256) * D_);
    const char* Bb = (const char*)(Bw + (size_t)e * H_ * D_ + (size_t)(blockIdx.x * 256) * D_);
    const int NI = (D_ / 64) / 2;  // 8

#define G1SA(T, HF) (Ab + (HF) * 128 * (D_ * 2) + (T) * 128)
#define G1SB(T, HF) (Bb + (HF) * 128 * (D_ * 2) + (T) * 128)

    // prologue: buf0 <- tile0 (all 4 halves), buf1 <- tile1 A0,B0
    STG(G1SA(0, 0), &lA[0][0][0]); STG(G1SA(0, 1), &lA[0][1][0]);
    STG(G1SB(0, 0), &lB[0][0][0]); STG(G1SB(0, 1), &lB[0][1][0]);
    STG(G1SA(1, 0), &lA[1][0][0]); STG(G1SB(1, 0), &lB[1][0][0]);
    VM4;       // 12 in flight -> oldest 8 (all of tile0) landed
    BARRIER;

#pragma unroll 1
    for (int i = 0; i < NI - 1; ++i) { const int t0 = 2 * i; EIGHT_PHASES(G1SA, G1SB, t0, 0); }
    { const int t0 = 2 * NI - 2; EIGHT_PHASES(G1SA, G1SB, t0, 1); }
#undef G1SA
#undef G1SB

#pragma unroll
    for (int am = 0; am < 8; ++am)
#pragma unroll
        for (int nt = 0; nt < 4; ++nt) {
            int n = blockIdx.x * 256 + (nt >> 1) * 128 + wc * 32 + (nt & 1) * 16 + lr;
            float bbv = b1[e * H_ + n];
#pragma unroll
            for (int r = 0; r < 4; ++r) {
                int mrow = blockIdx.y * 256 + (am >> 2) * 128 + wr * 64 + (am & 3) * 16 + quad * 4 + r;
                float v = acc[am][nt][r] + bbv;
                v = v / (1.f + __expf(-v)) * wk;
                hbuf[((size_t)lp * hRows + mrow) * H_ + n] = f2bf(v);
            }
        }
}

// GEMM2: out[b] = sum_kp hbuf[b*2+kp] @ W2T[e_kp]^T + sum w*b2; virtual K = 2*H_, ld=H_
__global__ __launch_bounds__(512) void gemm2_v4(
    const u16* __restrict__ hbuf, const u16* __restrict__ Bw,
    const float* __restrict__ b2, const int* __restrict__ eidx,
    const float* __restrict__ wgate, float* __restrict__ out,
    int s0, int hRows) {
    __shared__ __align__(16) u16 lA[2][2][8192];
    __shared__ __align__(16) u16 lB[2][2][8192];
    SETUP_V4(H_ * 2)
    const int bz = blockIdx.z;
    const int e0 = eidx[bz * 2], e1 = eidx[bz * 2 + 1];
    const float w0 = wgate[bz * 2], w1 = wgate[bz * 2 + 1];
    const char* Ab0 = (const char*)(hbuf + ((size_t)(bz * 2) * hRows + blockIdx.y * 256) * H_);
    const char* Ab1 = (const char*)(hbuf + ((size_t)(bz * 2 + 1) * hRows + blockIdx.y * 256) * H_);
    const char* Bb0 = (const char*)(Bw + (size_t)e0 * D_ * H_ + (size_t)(blockIdx.x * 256) * H_);
    const char* Bb1 = (const char*)(Bw + (size_t)e1 * D_ * H_ + (size_t)(blockIdx.x * 256) * H_);
    const int NI = (2 * H_ / 64) / 2;  // 64

#define G2SA(T, HF) ((((T) & 64) ? Ab1 : Ab0) + (HF) * 128 * (H_ * 2) + ((T) & 63) * 128)
#define G2SB(T, HF) ((((T) & 64) ? Bb1 : Bb0) + (HF) * 128 * (H_ * 2) + ((T) & 63) * 128)

    STG(G2SA(0, 0), &lA[0][0][0]); STG(G2SA(0, 1), &lA[0][1][0]);
    STG(G2SB(0, 0), &lB[0][0][0]); STG(G2SB(0, 1), &lB[0][1][0]);
    STG(G2SA(1, 0), &lA[1][0][0]); STG(G2SB(1, 0), &lB[1][0][0]);
    VM4;
    BARRIER;

#pragma unroll 1
    for (int i = 0; i < NI - 1; ++i) { const int t0 = 2 * i; EIGHT_PHASES(G2SA, G2SB, t0, 0); }
    { const int t0 = 2 * NI - 2; EIGHT_PHASES(G2SA, G2SB, t0, 1); }
#undef G2SA
#undef G2SB

#pragma unroll
    for (int am = 0; am < 8; ++am)
#pragma unroll
        for (int nt = 0; nt < 4; ++nt) {
            int n = blockIdx.x * 256 + (nt >> 1) * 128 + wc * 32 + (nt & 1) * 16 + lr;
            float bbv = w0 * b2[e0 * D_ + n] + w1 * b2[e1 * D_ + n];
#pragma unroll
            for (int r = 0; r < 4; ++r) {
                int mrow = blockIdx.y * 256 + (am >> 2) * 128 + wr * 64 + (am & 3) * 16 + quad * 4 + r;
                out[((size_t)bz * S_ + s0 + mrow) * D_ + n] = acc[am][nt][r] + bbv;
            }
        }
}

// ===================== old 128x128 2-phase GEMMs (tier-C fallback only) =====================
template<int BT>
__global__ __launch_bounds__(256) void gemm1_kernel(
    const void* __restrict__ A_, const void* __restrict__ Bw_,
    const float* __restrict__ b1, const int* __restrict__ eidx,
    const float* __restrict__ wgate, u16* __restrict__ hbuf,
    int s0, int hRows, int pbase) {
    __shared__ __align__(16) u16 ldsA[1024 * 8];
    __shared__ __align__(16) u16 ldsB[1024 * 8];
    int tid = threadIdx.x, lane = tid & 63, wid = tid >> 6;
    int wm = wid & 1, wn = wid >> 1, lr = lane & 15, quad = lane >> 4;
    int lp = blockIdx.z, p = pbase + lp, b = p >> 1;
    int e = eidx[p];
    float wk = wgate[p];
    size_t arow = (size_t)(b * S_ + s0 + blockIdx.y * 128);
    floatx4 acc[4][4] = {};
    for (int kk = 0; kk < D_; kk += 64) {
        if (BT == 0) {
            stage((const u16*)A_ + arow * D_ + kk, D_, ldsA, tid);
            stage((const u16*)Bw_ + (size_t)e * H_ * D_ +
                  (size_t)(blockIdx.x * 128) * D_ + kk, D_, ldsB, tid);
        } else {
            stageF((const float*)A_ + arow * D_ + kk, D_, ldsA, tid);
            stageKTF((const float*)Bw_ + (size_t)e * D_ * H_ +
                     (size_t)kk * H_ + blockIdx.x * 128, H_, ldsB, tid);
        }
        __syncthreads();
#pragma unroll
        for (int ks = 0; ks < 2; ++ks) {
            bf16x8 af[4], bfr[4];
#pragma unroll
            for (int t = 0; t < 4; ++t) {
                af[t]  = fragld(ldsA, wm * 64 + t * 16 + lr, ks * 4 + quad);
                bfr[t] = fragld(ldsB, wn * 64 + t * 16 + lr, ks * 4 + quad);
            }
#pragma unroll
            for (int mt = 0; mt < 4; ++mt)
#pragma unroll
                for (int nt = 0; nt < 4; ++nt)
                    acc[mt][nt] = __builtin_amdgcn_mfma_f32_16x16x32_bf16(
                        af[mt], bfr[nt], acc[mt][nt], 0, 0, 0);
        }
        __syncthreads();
    }
#pragma unroll
    for (int mt = 0; mt < 4; ++mt)
#pragma unroll
        for (int nt = 0; nt < 4; ++nt) {
            int n = blockIdx.x * 128 + wn * 64 + nt * 16 + lr;
            float bb = b1[e * H_ + n];
#pragma unroll
            for (int r = 0; r < 4; ++r) {
                int mrow = blockIdx.y * 128 + wm * 64 + mt * 16 + quad * 4 + r;
                float v = acc[mt][nt][r] + bb;
                v = v / (1.f + __expf(-v)) * wk;
                hbuf[((size_t)lp * hRows + mrow) * H_ + n] = f2bf(v);
            }
        }
}

template<int BT>
__global__ __launch_bounds__(256) void gemm2_kernel(
    const u16* __restrict__ hbuf, const void* __restrict__ Bw_,
    const float* __restrict__ b2, const int* __restrict__ eidx,
    const float* __restrict__ wgate, float* __restrict__ out,
    int s0, int hRows, int bbase) {
    __shared__ __align__(16) u16 ldsA[1024 * 8];
    __shared__ __align__(16) u16 ldsB[1024 * 8];
    int tid = threadIdx.x, lane = tid & 63, wid = tid >> 6;
    int wm = wid & 1, wn = wid >> 1, lr = lane & 15, quad = lane >> 4;
    int lb = blockIdx.z, b = bbase + lb;
    floatx4 acc[4][4] = {};
    for (int kp = 0; kp < 2; ++kp) {
        int e = eidx[b * 2 + kp];
        const u16* Abase = hbuf + ((size_t)(lb * 2 + kp) * hRows + blockIdx.y * 128) * H_;
        for (int kk = 0; kk < H_; kk += 64) {
            stage(Abase + kk, H_, ldsA, tid);
            if (BT == 0)
                stage((const u16*)Bw_ + (size_t)e * D_ * H_ +
                      (size_t)(blockIdx.x * 128) * H_ + kk, H_, ldsB, tid);
            else
                stageKTF((const float*)Bw_ + (size_t)e * H_ * D_ +
                         (size_t)kk * D_ + blockIdx.x * 128, D_, ldsB, tid);
            __syncthreads();
#pragma unroll
            for (int ks = 0; ks < 2; ++ks) {
                bf16x8 af[4], bfr[4];
#pragma unroll
                for (int t = 0; t < 4; ++t) {
                    af[t]  = fragld(ldsA, wm * 64 + t * 16 + lr, ks * 4 + quad);
                    bfr[t] = fragld(ldsB, wn * 64 + t * 16 + lr, ks * 4 + quad);
                }
#pragma unroll
                for (int mt = 0; mt < 4; ++mt)
#pragma unroll
                    for (int nt = 0; nt < 4; ++nt)
                        acc[mt][nt] = __builtin_amdgcn_mfma_f32_16x16x32_bf16(
                            af[mt], bfr[nt], acc[mt][nt], 0, 0, 0);
            }
            __syncthreads();
        }
    }
    int e0 = eidx[b * 2], e1 = eidx[b * 2 + 1];
    float w0 = wgate[b * 2], w1 = wgate[b * 2 + 1];
#pragma unroll
    for (int mt = 0; mt < 4; ++mt)
#pragma unroll
        for (int nt = 0; nt < 4; ++nt) {
            int n = blockIdx.x * 128 + wn * 64 + nt * 16 + lr;
            float bb = w0 * b2[e0 * D_ + n] + w1 * b2[e1 * D_ + n];
#pragma unroll
            for (int r = 0; r < 4; ++r) {
                int mrow = blockIdx.y * 128 + wm * 64 + mt * 16 + quad * 4 + r;
                out[((size_t)b * S_ + s0 + mrow) * D_ + n] = acc[mt][nt][r] + bb;
            }
        }
}

extern "C" void kernel_launch(void* const* d_in, const int* in_sizes, int n_in,
                              void* d_out, int out_size, void* d_ws, size_t ws_size,
                              hipStream_t stream) {
    const float* x   = (const float*)d_in[0];
    const float* Wg1 = (const float*)d_in[1];
    const float* bg1 = (const float*)d_in[2];
    const float* Wg2 = (const float*)d_in[3];
    const float* bg2 = (const float*)d_in[4];
    const float* W1  = (const float*)d_in[5];
    const float* b1  = (const float*)d_in[6];
    const float* W2  = (const float*)d_in[7];
    const float* b2  = (const float*)d_in[8];
    float* out = (float*)d_out;
    char* ws = (char*)d_ws;

    float* ri    = (float*)ws;                 // 32 KB
    float* gh    = (float*)(ws + 32768);       // 32 KB
    float* wgate = (float*)(ws + 65536);       // 64 B
    int*   eidx  = (int*)(ws + 65792);         // 64 B
    float* part  = (float*)(ws + 131072);      // 256 KB mean partials

    const size_t base = (size_t)1 << 20;                  // 1 MiB small-buffer region
    const size_t szXb = (size_t)B_ * S_ * D_ * 2;         // 32 MiB bf16 x
    const size_t szW  = (size_t)E_ * D_ * H_ * 2;         // 64 MiB per bf16 weight set
    const size_t rowB = (size_t)H_ * 2;                   // 8 KiB per hbuf row

    mean1_kernel<<<dim3(B_ * 4, 8), 256, 0, stream>>>(x, part);
    mean2_kernel<<<dim3(B_ * 4), 256, 0, stream>>>(part, ri);
    gate1_kernel<<<dim3(B_ * 4), 256, 0, stream>>>(ri, Wg1, bg1, gh);
    gate2_kernel<<<1, 64, 0, stream>>>(gh, Wg2, bg2, wgate, eidx, out);

    auto clampSc256 = [](long v) -> int {
        long s = v & ~255L;
        if (s > S_) s = S_;
        if (s < 256) s = 256;
        return (int)s;
    };
    auto clampSc128 = [](long v) -> int {
        long s = v & ~127L;
        if (s > S_) s = S_;
        if (s < 128) s = 128;
        return (int)s;
    };

    if (ws_size >= base + szXb + 2 * szW + (size_t)16 * 256 * rowB) {
        // ---- Tier A: bf16 x + transposed bf16 weights + hbuf; 256x256 8-phase GEMMs ----
        u16* xb   = (u16*)(ws + base);
        u16* W1T  = (u16*)(ws + base + szXb);
        u16* W2T  = (u16*)(ws + base + szXb + szW);
        u16* hbuf = (u16*)(ws + base + szXb + 2 * szW);
        int Sc = clampSc256((long)((ws_size - base - szXb - 2 * szW) / ((size_t)16 * rowB)));
        convx_kernel<<<dim3((B_ * S_ * D_) / (256 * 8)), 256, 0, stream>>>(x, xb);
        convT_kernel<<<dim3(H_ / 64, D_ / 64, E_), 256, 0, stream>>>(W1, W1T, D_, H_);
        convT_kernel<<<dim3(D_ / 64, H_ / 64, E_), 256, 0, stream>>>(W2, W2T, H_, D_);
        for (int s0 = 0; s0 < S_; s0 += Sc) {
            int rows = (S_ - s0 < Sc) ? (S_ - s0) : Sc;
            gemm1_v4<<<dim3(H_ / 256, rows / 256, B_ * 2), 512, 0, stream>>>(
                xb, W1T, b1, eidx, wgate, hbuf, s0, Sc);
            gemm2_v4<<<dim3(D_ / 256, rows / 256, B_), 512, 0, stream>>>(
                hbuf, W2T, b2, eidx, wgate, out, s0, Sc);
        }
    } else {
        // ---- Tier C: no conversion buffers; stage fp32->bf16 through LDS (old path) ----
        u16* hbuf = (u16*)(ws + base);
        long avail = (long)ws_size - (long)base;
        if (avail < 0) avail = 0;
        int Sc = clampSc128(avail / (long)(2 * rowB));
        for (int b = 0; b < B_; ++b) {
            for (int s0 = 0; s0 < S_; s0 += Sc) {
                int rows = (S_ - s0 < Sc) ? (S_ - s0) : Sc;
                gemm1_kernel<1><<<dim3(H_ / 128, rows / 128, 2), 256, 0, stream>>>(
                    x, W1, b1, eidx, wgate, hbuf, s0, Sc, b * 2);
                gemm2_kernel<1><<<dim3(D_ / 128, rows / 128, 1), 256, 0, stream>>>(
                    hbuf, W2, b2, eidx, wgate, out, s0, Sc, b);
            }
        }
    }
}